// Round 1
// baseline (612.777 us; speedup 1.0000x reference)
//
#include <hip/hip_runtime.h>

#define THREADS 256

// ---------- edge_index dtype probe: int64 high-words (values in [0,2^31)) are all 0 ----------
__global__ void detect_kernel(const unsigned int* ei_words, int* flag_int64, long long n_words) {
    __shared__ int nonzero;
    if (threadIdx.x == 0) nonzero = 0;
    __syncthreads();
    long long w = 2LL * threadIdx.x + 1;   // odd word positions = int64 high words
    if (w < n_words) {
        if (ei_words[w] != 0u) atomicOr(&nonzero, 1);
    }
    __syncthreads();
    if (threadIdx.x == 0) *flag_int64 = (nonzero == 0) ? 1 : 0;
}

__global__ void convert_kernel(const void* __restrict__ ei, const int* __restrict__ flag_int64,
                               int* __restrict__ out, long long n) {
    long long i = (long long)blockIdx.x * blockDim.x + threadIdx.x;
    if (i >= n) return;
    if (*flag_int64)
        out[i] = (int)((const long long*)ei)[i];
    else
        out[i] = ((const int*)ei)[i];
}

// ---------- degree histogram over dst ----------
__global__ void hist_kernel(const int* __restrict__ dst, int* __restrict__ count, int E) {
    int e = blockIdx.x * blockDim.x + threadIdx.x;
    if (e < E) atomicAdd(&count[dst[e]], 1);
}

// ---------- 3-kernel exclusive scan (1024 elems / block) ----------
__global__ void scan_blocks_kernel(const int* __restrict__ count, int* __restrict__ rowptr,
                                   int* __restrict__ partials, int N) {
    __shared__ int sd[THREADS];
    int tid = threadIdx.x;
    int base = blockIdx.x * 1024 + tid * 4;
    int c0 = (base + 0 < N) ? count[base + 0] : 0;
    int c1 = (base + 1 < N) ? count[base + 1] : 0;
    int c2 = (base + 2 < N) ? count[base + 2] : 0;
    int c3 = (base + 3 < N) ? count[base + 3] : 0;
    int tsum = c0 + c1 + c2 + c3;
    sd[tid] = tsum;
    __syncthreads();
    for (int off = 1; off < THREADS; off <<= 1) {
        int t = (tid >= off) ? sd[tid - off] : 0;
        __syncthreads();
        sd[tid] += t;
        __syncthreads();
    }
    int excl = sd[tid] - tsum;
    if (base + 0 < N) rowptr[base + 0] = excl;
    if (base + 1 < N) rowptr[base + 1] = excl + c0;
    if (base + 2 < N) rowptr[base + 2] = excl + c0 + c1;
    if (base + 3 < N) rowptr[base + 3] = excl + c0 + c1 + c2;
    if (tid == THREADS - 1) partials[blockIdx.x] = sd[tid];
}

__global__ void scan_partials_kernel(int* __restrict__ partials, int* __restrict__ rowptr_last, int B) {
    __shared__ int sd[128];
    int tid = threadIdx.x;  // 128 threads, B <= 128
    int v = (tid < B) ? partials[tid] : 0;
    sd[tid] = v;
    __syncthreads();
    for (int off = 1; off < 128; off <<= 1) {
        int t = (tid >= off) ? sd[tid - off] : 0;
        __syncthreads();
        sd[tid] += t;
        __syncthreads();
    }
    if (tid < B) partials[tid] = sd[tid] - v;     // exclusive
    if (tid == 127) rowptr_last[0] = sd[127];     // grand total -> rowptr[N]
}

__global__ void scan_add_kernel(int* __restrict__ rowptr, const int* __restrict__ partials, int N) {
    int tid = threadIdx.x;
    int base = blockIdx.x * 1024 + tid * 4;
    int add = partials[blockIdx.x];
    if (base + 0 < N) rowptr[base + 0] += add;
    if (base + 1 < N) rowptr[base + 1] += add;
    if (base + 2 < N) rowptr[base + 2] += add;
    if (base + 3 < N) rowptr[base + 3] += add;
}

// ---------- dinv = 1/sqrt(deg), deg = count + 1 (self loop) ----------
__global__ void dinv_kernel(const int* __restrict__ count, float* __restrict__ dinv, int N) {
    int i = blockIdx.x * blockDim.x + threadIdx.x;
    if (i < N) dinv[i] = 1.0f / sqrtf((float)(count[i] + 1));
}

// ---------- CSR scatter: col[slot(dst)] = src ----------
__global__ void scatter_kernel(const int* __restrict__ src, const int* __restrict__ dst,
                               const int* __restrict__ rowptr, int* __restrict__ fill,
                               int* __restrict__ col, int E) {
    int e = blockIdx.x * blockDim.x + threadIdx.x;
    if (e >= E) return;
    int d = dst[e];
    int pos = rowptr[d] + atomicAdd(&fill[d], 1);
    col[pos] = src[e];
}

// ---------- dense transform: out = (h @ W^T) * dinv[n] ----------
__global__ void dense_kernel(const float* __restrict__ h, const float* __restrict__ W,
                             const float* __restrict__ dinv, float* __restrict__ out, int N) {
    __shared__ float Wt[1024];   // Wt[k*32 + j] = W[j*32 + k]
    __shared__ float hs[THREADS];
    int tid = threadIdx.x;
    for (int idx = tid; idx < 1024; idx += THREADS) {
        int r = idx >> 5, c = idx & 31;
        Wt[c * 32 + r] = W[idx];
    }
    int gid = blockIdx.x * THREADS + tid;
    int total = N * 32;
    if (gid < total) hs[tid] = h[gid];
    __syncthreads();
    if (gid >= total) return;
    int ln = tid >> 5;   // local node
    int j = tid & 31;    // feature
    const float* hr = hs + ln * 32;
    float s = 0.f;
#pragma unroll
    for (int k = 0; k < 32; ++k) s = fmaf(hr[k], Wt[k * 32 + j], s);
    out[gid] = s * dinv[gid >> 5];
}

// ---------- aggregate: out = relu(dinv[n] * (self + sum_{nbr} ht[src]) + b[j]) ----------
__global__ void agg_kernel(const float* __restrict__ ht, const int* __restrict__ rowptr,
                           const int* __restrict__ col, const float* __restrict__ dinv,
                           const float* __restrict__ bias, float* __restrict__ out, int N) {
    int gid = blockIdx.x * THREADS + threadIdx.x;
    int n = gid >> 5;
    if (n >= N) return;
    int j = gid & 31;
    float s = ht[gid];                 // self loop (dinv[n] factor applied at end)
    int p = rowptr[n], end = rowptr[n + 1];
    for (; p + 4 <= end; p += 4) {
        int s0 = col[p], s1 = col[p + 1], s2 = col[p + 2], s3 = col[p + 3];
        float v0 = ht[s0 * 32 + j];
        float v1 = ht[s1 * 32 + j];
        float v2 = ht[s2 * 32 + j];
        float v3 = ht[s3 * 32 + j];
        s += (v0 + v1) + (v2 + v3);
    }
    for (; p < end; ++p) s += ht[col[p] * 32 + j];
    out[gid] = fmaxf(fmaf(dinv[n], s, bias[j]), 0.f);
}

extern "C" void kernel_launch(void* const* d_in, const int* in_sizes, int n_in,
                              void* d_out, int out_size, void* d_ws, size_t ws_size,
                              hipStream_t stream) {
    const float* x  = (const float*)d_in[0];
    const void*  ei = d_in[1];
    const float* W1 = (const float*)d_in[2];
    const float* b1 = (const float*)d_in[3];
    const float* W2 = (const float*)d_in[4];
    const float* b2 = (const float*)d_in[5];
    float* out = (float*)d_out;

    int N = in_sizes[0] / 32;
    long long twoE = (long long)in_sizes[1];
    int E = (int)(twoE / 2);

    char* ws = (char*)d_ws;
    size_t o = 0;
    auto alloc = [&](size_t bytes) { size_t r = o; o += (bytes + 255) & ~(size_t)255; return r; };
    int*   flag     = (int*)(ws + alloc(4));
    int*   e32      = (int*)(ws + alloc((size_t)twoE * 4));   // [src | dst]
    int*   count    = (int*)(ws + alloc((size_t)N * 4));
    int*   fill     = (int*)(ws + alloc((size_t)N * 4));
    int*   rowptr   = (int*)(ws + alloc((size_t)(N + 1) * 4));
    int*   partials = (int*)(ws + alloc(512));
    float* dinv     = (float*)(ws + alloc((size_t)N * 4));
    int*   col      = (int*)(ws + alloc((size_t)E * 4));
    float* ht       = (float*)(ws + alloc((size_t)N * 32 * 4));
    float* h1       = (float*)(ws + alloc((size_t)N * 32 * 4));
    int* src32 = e32;
    int* dst32 = e32 + E;

    hipMemsetAsync(count, 0, (size_t)N * 4, stream);
    hipMemsetAsync(fill, 0, (size_t)N * 4, stream);

    detect_kernel<<<1, 256, 0, stream>>>((const unsigned int*)ei, flag, twoE);
    convert_kernel<<<(int)((twoE + 255) / 256), 256, 0, stream>>>(ei, flag, e32, twoE);

    hist_kernel<<<(E + 255) / 256, 256, 0, stream>>>(dst32, count, E);

    int SB = (N + 1023) / 1024;   // 98 blocks for N=100000 (must be <=128)
    scan_blocks_kernel<<<SB, THREADS, 0, stream>>>(count, rowptr, partials, N);
    scan_partials_kernel<<<1, 128, 0, stream>>>(partials, rowptr + N, SB);
    scan_add_kernel<<<SB, THREADS, 0, stream>>>(rowptr, partials, N);

    dinv_kernel<<<(N + 255) / 256, 256, 0, stream>>>(count, dinv, N);
    scatter_kernel<<<(E + 255) / 256, 256, 0, stream>>>(src32, dst32, rowptr, fill, col, E);

    int GB = (N * 32 + THREADS - 1) / THREADS;
    dense_kernel<<<GB, THREADS, 0, stream>>>(x, W1, dinv, ht, N);
    agg_kernel<<<GB, THREADS, 0, stream>>>(ht, rowptr, col, dinv, b1, h1, N);
    dense_kernel<<<GB, THREADS, 0, stream>>>(h1, W2, dinv, ht, N);
    agg_kernel<<<GB, THREADS, 0, stream>>>(ht, rowptr, col, dinv, b2, out, N);
}